// Round 6
// baseline (156.994 us; speedup 1.0000x reference)
//
#include <hip/hip_runtime.h>
#include <hip/hip_bf16.h>
#include <stdint.h>

#define EMB   2048
#define TOK   2048
#define NH    32
#define NKV   8
#define HD    64
#define QKVN  3072   // 2048 q + 512 k + 512 v

typedef __attribute__((ext_vector_type(8))) short bf16x8;   // 8 bf16 = 4 VGPRs
typedef __attribute__((ext_vector_type(4))) float f32x4;
typedef __attribute__((ext_vector_type(16))) float f32x16;
typedef __attribute__((ext_vector_type(4))) unsigned int u32x4;

__device__ __forceinline__ void gld16(const void* g, void* l) {
  auto gp = reinterpret_cast<const int __attribute__((address_space(1)))*>(
      reinterpret_cast<uintptr_t>(g));
  auto lp = reinterpret_cast<int __attribute__((address_space(3)))*>(
      reinterpret_cast<uintptr_t>(l));
  __builtin_amdgcn_global_load_lds(gp, lp, 16, 0, 0);
}

__device__ __forceinline__ unsigned int cvtpk_bf16(float lo, float hi) {
  unsigned int r;
  asm("v_cvt_pk_bf16_f32 %0, %1, %2" : "=v"(r) : "v"(lo), "v"(hi));
  return r;
}
__device__ __forceinline__ void pl32swap(unsigned int &a, unsigned int &b) {
  asm volatile("v_permlane32_swap_b32 %0, %1" : "+v"(a), "+v"(b));
}
__device__ __forceinline__ float fexp2(float x) {  // v_exp_f32 IS 2^x
  float r;
  asm("v_exp_f32 %0, %1" : "=v"(r) : "v"(x));
  return r;
}

// ---------------------------------------------------------------- cast fp32->bf16
__global__ void cast_all(const float* __restrict__ x,  const float* __restrict__ wq,
                         const float* __restrict__ wk, const float* __restrict__ wv,
                         const float* __restrict__ wo,
                         __hip_bfloat16* __restrict__ xb,
                         __hip_bfloat16* __restrict__ wc,
                         __hip_bfloat16* __restrict__ wob) {
  const size_t M4 = (size_t)4 * 1024 * 1024;
  const size_t M1 = (size_t)1024 * 1024;
  size_t i = ((size_t)blockIdx.x * 256 + threadIdx.x) * 4;
  const float* src;
  __hip_bfloat16* dst;
  if (i < M4)                    { src = x  + i;                 dst = xb  + i; }
  else if (i < 2*M4)             { src = wq + (i - M4);          dst = wc  + (i - M4); }
  else if (i < 2*M4 + M1)        { src = wk + (i - 2*M4);        dst = wc  + M4 + (i - 2*M4); }
  else if (i < 2*M4 + 2*M1)      { src = wv + (i - 2*M4 - M1);   dst = wc  + M4 + M1 + (i - 2*M4 - M1); }
  else                           { src = wo + (i - 2*M4 - 2*M1); dst = wob + (i - 2*M4 - 2*M1); }
  float4 v = *reinterpret_cast<const float4*>(src);
  dst[0] = __float2bfloat16(v.x);
  dst[1] = __float2bfloat16(v.y);
  dst[2] = __float2bfloat16(v.z);
  dst[3] = __float2bfloat16(v.w);
}

// ---------------------------------------------------------------- GEMM  C = A * B^T
// 8-phase-family template (T2+T3+T4+T5) adapted: BM=256, BN=128, BK=64,
// 8 waves (2x4), per-wave out 128x32; 2 MFMA-phases of 16 per K-tile.
// 3-slot LDS rotation (stage tile t+2 during tile t) -> counted vmcnt(6),
// never 0 in steady state; st_16x32 swizzle (byte ^= ((byte>>9)&1)<<5) via
// inverse-swizzled global source + swizzled ds_read (involution, rule #21).
#define SLOT_BYTES (48 * 1024)   // A 32KB + B 16KB
#define B_OFF      (32 * 1024)

__global__ __launch_bounds__(512) void gemm8(const __hip_bfloat16* __restrict__ A,
                                             const __hip_bfloat16* __restrict__ B,
                                             float* __restrict__ C,
                                             int M, int N, int K) {
  extern __shared__ char lds[];          // 3 * 48 KB
  const int nbc = N >> 7;                // N / 128
  const int nwg = gridDim.x;             // multiple of 8 for both GEMMs
  int bid = blockIdx.x;
  bid = (bid & 7) * (nwg >> 3) + (bid >> 3);   // bijective XCD swizzle
  const int br = bid / nbc, bc = bid % nbc;

  const int tid  = threadIdx.x;
  const int w    = tid >> 6;             // wave 0..7
  const int lane = tid & 63;
  const int wr   = w >> 2, wc = w & 3;   // 2 x 4 wave grid
  const int l15  = lane & 15, lg = lane >> 4;
  const int swz  = (l15 & 4) << 3;       // 0 or 32 (read-side XOR)

  const __hip_bfloat16* Ag = A + (size_t)br * 256 * K;
  const __hip_bfloat16* Bg = B + (size_t)bc * 128 * K;

  // staging geometry: lane's 16B chunk at phys = chunk*1024 + lane*16.
  // logical = phys ^ (bit9(phys)<<5); bit9(phys) = (lane&32)!=0.
  const int srow = lane >> 3;                                   // row within 8-row group
  const int scol = ((lane & 7) * 8) ^ ((lane & 32) ? 16 : 0);   // inverse-swz bf16 col

  auto stage_unit = [&](const __hip_bfloat16* src, char* dst_base) {
#pragma unroll
    for (int i = 0; i < 2; ++i) {
      const int chunk = w * 2 + i;       // wave-uniform
      gld16(src + (size_t)(chunk * 8 + srow) * K + scol, dst_base + chunk * 1024);
    }
  };

  f32x4 acc[8][2];
#pragma unroll
  for (int m = 0; m < 8; ++m)
#pragma unroll
    for (int n = 0; n < 2; ++n) acc[m][n] = (f32x4){0.f, 0.f, 0.f, 0.f};

  const int nt = K >> 6;                 // 32 K-tiles

  // ---- prologue: stage tiles 0 and 1 (slots 0,1); drain tile 0 (keep 6 = t1)
  {
    char* s0 = lds;
    char* s1 = lds + SLOT_BYTES;
    stage_unit(Ag,                    s0);
    stage_unit(Ag + (size_t)128 * K,  s0 + 16384);
    stage_unit(Bg,                    s0 + B_OFF);
    stage_unit(Ag + 64,               s1);
    stage_unit(Ag + (size_t)128 * K + 64, s1 + 16384);
    stage_unit(Bg + 64,               s1 + B_OFF);
  }
  asm volatile("s_waitcnt vmcnt(6)" ::: "memory");
  __builtin_amdgcn_s_barrier();

  int slc = 0, sls = 2;                  // current slot, staging slot ((t+2)%3)
  for (int t = 0; t < nt; ++t) {
    const char* sa = lds + slc * SLOT_BYTES;
    const char* sb = sa + B_OFF;
    char* stg = lds + sls * SLOT_BYTES;
    const int kt2 = (t + 2) * 64;
    const bool do_stage = (t + 2) < nt;

    bf16x8 afr[4][2], bfr[2][2];
    // ================= phase 1 (mh = 0): ds-load A m0-3 + B, stage A(t+2)
#pragma unroll
    for (int m = 0; m < 4; ++m)
#pragma unroll
      for (int kk = 0; kk < 2; ++kk)
        afr[m][kk] = *reinterpret_cast<const bf16x8*>(
            sa + (((wr * 128 + m * 16 + l15) * 128 + kk * 64 + lg * 16) ^ swz));
#pragma unroll
    for (int n = 0; n < 2; ++n)
#pragma unroll
      for (int kk = 0; kk < 2; ++kk)
        bfr[n][kk] = *reinterpret_cast<const bf16x8*>(
            sb + (((wc * 32 + n * 16 + l15) * 128 + kk * 64 + lg * 16) ^ swz));
    if (do_stage) {
      stage_unit(Ag + kt2,                   stg);
      stage_unit(Ag + (size_t)128 * K + kt2, stg + 16384);
    }
    __builtin_amdgcn_s_barrier();
    asm volatile("s_waitcnt lgkmcnt(0)" ::: "memory");
    __builtin_amdgcn_sched_barrier(0);
    __builtin_amdgcn_s_setprio(1);
#pragma unroll
    for (int m = 0; m < 4; ++m)
#pragma unroll
      for (int n = 0; n < 2; ++n)
#pragma unroll
        for (int kk = 0; kk < 2; ++kk)
          acc[m][n] = __builtin_amdgcn_mfma_f32_16x16x32_bf16(afr[m][kk], bfr[n][kk],
                                                              acc[m][n], 0, 0, 0);
    __builtin_amdgcn_s_setprio(0);
    __builtin_amdgcn_s_barrier();

    // ================= phase 2 (mh = 1): ds-load A m4-7 (B reused), stage B(t+2)
#pragma unroll
    for (int m = 0; m < 4; ++m)
#pragma unroll
      for (int kk = 0; kk < 2; ++kk)
        afr[m][kk] = *reinterpret_cast<const bf16x8*>(
            sa + (((wr * 128 + 64 + m * 16 + l15) * 128 + kk * 64 + lg * 16) ^ swz));
    if (do_stage) stage_unit(Bg + kt2, stg + B_OFF);
    __builtin_amdgcn_s_barrier();
    asm volatile("s_waitcnt lgkmcnt(0)" ::: "memory");
    __builtin_amdgcn_sched_barrier(0);
    __builtin_amdgcn_s_setprio(1);
#pragma unroll
    for (int m = 0; m < 4; ++m)
#pragma unroll
      for (int n = 0; n < 2; ++n)
#pragma unroll
        for (int kk = 0; kk < 2; ++kk)
          acc[4 + m][n] = __builtin_amdgcn_mfma_f32_16x16x32_bf16(afr[m][kk], bfr[n][kk],
                                                                  acc[4 + m][n], 0, 0, 0);
    __builtin_amdgcn_s_setprio(0);
    // boundary: counted vmcnt (6 = tile t+2's in-flight loads); drain at tail
    if (t < nt - 2) asm volatile("s_waitcnt vmcnt(6)" ::: "memory");
    else            asm volatile("s_waitcnt vmcnt(0)" ::: "memory");
    __builtin_amdgcn_s_barrier();

    slc = (slc == 2) ? 0 : slc + 1;
    sls = (sls == 2) ? 0 : sls + 1;
  }

  // ---- epilogue: C-write (row = lg*4 + reg, col = l15 per C/D layout)
  const int row0 = br * 256 + wr * 128;
  const int col0 = bc * 128 + wc * 32;
#pragma unroll
  for (int m = 0; m < 8; ++m)
#pragma unroll
    for (int n = 0; n < 2; ++n)
#pragma unroll
      for (int r = 0; r < 4; ++r)
        C[(size_t)(row0 + m * 16 + lg * 4 + r) * N + col0 + n * 16 + l15] = acc[m][n][r];
}

// ---------------------------------------------------------------- RoPE + cast to tiled fragment layouts
// Q gets 1/sqrt(HD) * log2(e) folded in (attention uses exp2-domain softmax).
// Tile-chunk ("TC") layouts, one 32-token tile = 2048 bf16 = 4KB:
//   K/Q: elem (t,d) -> tile (t>>5), chunk c = (d>>4)*64 + ((d>>3)&1)*32 + (t&31), byte elem d&7
//   V:   elem (d,t) -> tile (t>>5), chunk c = ((t>>4)&1)*128 + (d>>5)*64 + ((t>>3)&1)*32 + (d&31), elem t&7
#define QSCALE 0.1803368801111243f   // 0.125 * log2(e)

__device__ __forceinline__ size_t kq_idx(int tile_row, int t, int d) {
  return ((size_t)tile_row) * 2048 +
         ((((d >> 4) * 64) + (((d >> 3) & 1) * 32) + (t & 31)) << 3) + (d & 7);
}

__global__ void rope_cast(const float* __restrict__ qkv,
                          const float* __restrict__ cosT, const float* __restrict__ sinT,
                          __hip_bfloat16* __restrict__ Qf,
                          __hip_bfloat16* __restrict__ Kf,
                          __hip_bfloat16* __restrict__ Vf) {
  const int QP = TOK * NH * (HD / 2);   // 2,097,152
  const int KP = TOK * NKV * (HD / 2);  //   524,288
  int idx = blockIdx.x * 256 + threadIdx.x;
  if (idx < QP) {
    int d = idx & 31, h = (idx >> 5) & 31, t = idx >> 10;
    const float* row = qkv + (size_t)t * QKVN + h * 64;
    float x1 = row[d], x2 = row[d + 32];
    float o1 = (x1 * cosT[t * 64 + d]      - x2 * sinT[t * 64 + d])      * QSCALE;
    float o2 = (x2 * cosT[t * 64 + d + 32] + x1 * sinT[t * 64 + d + 32]) * QSCALE;
    const int tile_row = h * 64 + (t >> 5);
    Qf[kq_idx(tile_row, t, d)]      = __float2bfloat16(o1);
    Qf[kq_idx(tile_row, t, d + 32)] = __float2bfloat16(o2);
  } else if (idx < QP + KP) {
    int j = idx - QP;
    int d = j & 31, hk = (j >> 5) & 7, t = j >> 8;
    const float* row = qkv + (size_t)t * QKVN + 2048 + hk * 64;
    float x1 = row[d], x2 = row[d + 32];
    float o1 = x1 * cosT[t * 64 + d]      - x2 * sinT[t * 64 + d];
    float o2 = x2 * cosT[t * 64 + d + 32] + x1 * sinT[t * 64 + d + 32];
    const int tile_row = hk * 64 + (t >> 5);
    Kf[kq_idx(tile_row, t, d)]      = __float2bfloat16(o1);
    Kf[kq_idx(tile_row, t, d + 32)] = __float2bfloat16(o2);
  } else {
    int vj = idx - QP - KP;               // d fastest -> coalesced qkv reads
    int d = vj & 63, t = (vj >> 6) & (TOK - 1), hk = vj >> 17;
    float v = qkv[(size_t)t * QKVN + 2560 + hk * 64 + d];
    const size_t tb = ((size_t)hk * 64 + (t >> 5)) * 2048;
    const int c = (((t >> 4) & 1) * 128) + ((d >> 5) * 64) + (((t >> 3) & 1) * 32) + (d & 31);
    Vf[tb + (c << 3) + (t & 7)] = __float2bfloat16(v);
  }
}

// ---------------------------------------------------------------- causal GQA flash attention
// 4-way kv-split per block (flash-decoding in-LDS). Unchanged from R4.
struct KVb { bf16x8 k0, k1, k2, k3, v00, v01, v10, v11; };

__device__ __forceinline__ void load_kv(KVb& b, const __hip_bfloat16* Kt,
                                        const __hip_bfloat16* Vt, int tile,
                                        int lane) {
  const __hip_bfloat16* Kp = Kt + (size_t)tile * 2048 + lane * 8;
  b.k0 = *reinterpret_cast<const bf16x8*>(Kp);
  b.k1 = *reinterpret_cast<const bf16x8*>(Kp + 512);
  b.k2 = *reinterpret_cast<const bf16x8*>(Kp + 1024);
  b.k3 = *reinterpret_cast<const bf16x8*>(Kp + 1536);
  const __hip_bfloat16* Vp = Vt + (size_t)tile * 2048 + lane * 8;
  b.v00 = *reinterpret_cast<const bf16x8*>(Vp);
  b.v10 = *reinterpret_cast<const bf16x8*>(Vp + 512);
  b.v01 = *reinterpret_cast<const bf16x8*>(Vp + 1024);
  b.v11 = *reinterpret_cast<const bf16x8*>(Vp + 1536);
}

__device__ __forceinline__ void compute_tile(const KVb& b, bool diag,
                                             const bf16x8 (&qf)[4],
                                             int l31, int hi,
                                             float& m, float& l,
                                             f32x16& oa0, f32x16& oa1) {
  f32x16 st;
#pragma unroll
  for (int r = 0; r < 16; ++r) st[r] = 0.f;
  st = __builtin_amdgcn_mfma_f32_32x32x16_bf16(b.k0, qf[0], st, 0, 0, 0);
  st = __builtin_amdgcn_mfma_f32_32x32x16_bf16(b.k1, qf[1], st, 0, 0, 0);
  st = __builtin_amdgcn_mfma_f32_32x32x16_bf16(b.k2, qf[2], st, 0, 0, 0);
  st = __builtin_amdgcn_mfma_f32_32x32x16_bf16(b.k3, qf[3], st, 0, 0, 0);

  float s[16];
#pragma unroll
  for (int r = 0; r < 16; ++r) s[r] = st[r];
  if (diag) {
#pragma unroll
    for (int r = 0; r < 16; ++r) {
      const int crow = (r & 3) + 8 * (r >> 2) + 4 * hi;
      s[r] = (crow <= l31) ? s[r] : -1e30f;
    }
  }
  float t0 = fmaxf(fmaxf(s[0], s[1]),   fmaxf(s[2], s[3]));
  float t1 = fmaxf(fmaxf(s[4], s[5]),   fmaxf(s[6], s[7]));
  float t2 = fmaxf(fmaxf(s[8], s[9]),   fmaxf(s[10], s[11]));
  float t3 = fmaxf(fmaxf(s[12], s[13]), fmaxf(s[14], s[15]));
  float rmax = fmaxf(fmaxf(t0, t1), fmaxf(t2, t3));
  rmax = fmaxf(rmax, __shfl_xor(rmax, 32));

  const int allskip = __all(rmax <= m + 8.0f);
  const float mnew = allskip ? m : fmaxf(m, rmax);
  float p[16];
#pragma unroll
  for (int r = 0; r < 16; ++r) p[r] = fexp2(s[r] - mnew);
  float u0 = (p[0] + p[1]) + (p[2] + p[3]);
  float u1 = (p[4] + p[5]) + (p[6] + p[7]);
  float u2 = (p[8] + p[9]) + (p[10] + p[11]);
  float u3 = (p[12] + p[13]) + (p[14] + p[15]);
  float rsum = (u0 + u1) + (u2 + u3);
  rsum += __shfl_xor(rsum, 32);
  if (!allskip) {
    const float resc = fexp2(m - mnew);
    l *= resc;
    m = mnew;
#pragma unroll
    for (int r = 0; r < 16; ++r) { oa0[r] *= resc; oa1[r] *= resc; }
  }
  l += rsum;

  unsigned int wpk[8];
#pragma unroll
  for (int j = 0; j < 8; ++j) wpk[j] = cvtpk_bf16(p[2 * j], p[2 * j + 1]);

  {
    unsigned int a0 = wpk[0], b0 = wpk[2];  pl32swap(a0, b0);
    unsigned int a1 = wpk[1], b1 = wpk[3];  pl32swap(a1, b1);
    u32x4 pw; pw[0] = a0; pw[1] = a1; pw[2] = b0; pw[3] = b1;
    bf16x8 pf = *reinterpret_cast<bf16x8*>(&pw);
    oa0 = __builtin_amdgcn_mfma_f32_32x32x16_bf16(b.v00, pf, oa0, 0, 0, 0);
    oa1 = __builtin_amdgcn_mfma_f32_32x32x16_bf16(b.v10, pf, oa1, 0, 0, 0);
  }
  {
    unsigned int a0 = wpk[4], b0 = wpk[6];  pl32swap(a0, b0);
    unsigned int a1 = wpk[5], b1 = wpk[7];  pl32swap(a1, b1);
    u32x4 pw; pw[0] = a0; pw[1] = a1; pw[2] = b0; pw[3] = b1;
    bf16x8 pf = *reinterpret_cast<bf16x8*>(&pw);
    oa0 = __builtin_amdgcn_mfma_f32_32x32x16_bf16(b.v01, pf, oa0, 0, 0, 0);
    oa1 = __builtin_amdgcn_mfma_f32_32x32x16_bf16(b.v11, pf, oa1, 0, 0, 0);
  }
}

__global__ __launch_bounds__(256) void attn4(const __hip_bfloat16* __restrict__ Qf,
                                             const __hip_bfloat16* __restrict__ Kf,
                                             const __hip_bfloat16* __restrict__ Vf,
                                             __hip_bfloat16* __restrict__ ctx) {
  const int h     = blockIdx.x & 31;
  const int strip = 63 - (blockIdx.x >> 5);
  const int hk    = h >> 2;
  const int tid   = threadIdx.x;
  const int w     = tid >> 6;
  const int lane  = tid & 63;
  const int l31   = lane & 31, hi = lane >> 5;
  const int q0    = strip * 32;
  const int nt    = strip + 1;

  __shared__ float part[4][64][33];
  __shared__ float mlb[4][2][32];

  const __hip_bfloat16* Kt = Kf + (size_t)hk * 64 * 2048;
  const __hip_bfloat16* Vt = Vf + (size_t)hk * 64 * 2048;

  const __hip_bfloat16* Qp = Qf + ((size_t)h * 64 + strip) * 2048 + lane * 8;
  bf16x8 qf[4];
#pragma unroll
  for (int ks = 0; ks < 4; ++ks)
    qf[ks] = *reinterpret_cast<const bf16x8*>(Qp + ks * 512);

  f32x16 oa0, oa1;
#pragma unroll
  for (int r = 0; r < 16; ++r) { oa0[r] = 0.f; oa1[r] = 0.f; }
  float m = -1e30f, l = 0.f;

  if (w < nt) {
    KVb A, B;
    load_kv(A, Kt, Vt, w, lane);
    int t = w;
    for (;;) {
      int nx = t + 4;
      if (nx < nt) load_kv(B, Kt, Vt, nx, lane);
      compute_tile(A, t == nt - 1, qf, l31, hi, m, l, oa0, oa1);
      t = nx;
      if (t >= nt) break;
      nx = t + 4;
      if (nx < nt) load_kv(A, Kt, Vt, nx, lane);
      compute_tile(B, t == nt - 1, qf, l31, hi, m, l, oa0, oa1);
      t = nx;
      if (t >= nt) break;
    }
  }

#pragma unroll
  for (int r = 0; r < 16; ++r) {
    const int d = (r & 3) + 8 * (r >> 2) + 4 * hi;
    part[w][d][l31]      = oa0[r];
    part[w][d + 32][l31] = oa1[r];
  }
  if (hi == 0) { mlb[w][0][l31] = m; mlb[w][1][l31] = l; }
  __syncthreads();

  const int d  = tid & 63;
  const int qg = tid >> 6;
#pragma unroll
  for (int qq = 0; qq < 8; ++qq) {
    const int q = qg * 8 + qq;
    const float m0 = mlb[0][0][q], m1 = mlb[1][0][q];
    const float m2 = mlb[2][0][q], m3 = mlb[3][0][q];
    const float M = fmaxf(fmaxf(m0, m1), fmaxf(m2, m3));
    const float s0 = fexp2(m0 - M), s1 = fexp2(m1 - M);
    const float s2 = fexp2(m2 - M), s3 = fexp2(m3 - M);
    const float L = mlb[0][1][q] * s0 + mlb[1][1][q] * s1 +
                    mlb[2][1][q] * s2 + mlb[3][1][q] * s3;
    const float val = part[0][d][q] * s0 + part[1][d][q] * s1 +
                      part[2][d][q] * s2 + part[3][d][q] * s3;
    ctx[(size_t)(q0 + q) * EMB + h * HD + d] = __float2bfloat16(val / L);
  }
}

// ---------------------------------------------------------------- launch
extern "C" void kernel_launch(void* const* d_in, const int* in_sizes, int n_in,
                              void* d_out, int out_size, void* d_ws, size_t ws_size,
                              hipStream_t stream) {
  const float* x    = (const float*)d_in[0];
  const float* cosT = (const float*)d_in[1];
  const float* sinT = (const float*)d_in[2];
  const float* Wq   = (const float*)d_in[3];
  const float* Wk   = (const float*)d_in[4];
  const float* Wv   = (const float*)d_in[5];
  const float* Wo   = (const float*)d_in[6];
  float* out = (float*)d_out;

  const size_t M4 = (size_t)4 * 1024 * 1024;
  const size_t M1 = (size_t)1024 * 1024;

  char* ws = (char*)d_ws;
  __hip_bfloat16* xb   = (__hip_bfloat16*)ws;
  __hip_bfloat16* Wc   = xb + M4;
  __hip_bfloat16* Wob  = Wc + (size_t)6 * M1;
  float*          qkv  = (float*)(Wob + M4);
  __hip_bfloat16* Qf   = (__hip_bfloat16*)(qkv + (size_t)TOK * QKVN);
  __hip_bfloat16* Kf   = Qf + (size_t)NH * TOK * HD;
  __hip_bfloat16* Vf   = Kf + (size_t)NKV * TOK * HD;
  __hip_bfloat16* ctxb = Vf + (size_t)NKV * HD * TOK;

  // allow 144 KB dynamic LDS for gemm8 (deterministic, idempotent)
  hipFuncSetAttribute(reinterpret_cast<const void*>(gemm8),
                      hipFuncAttributeMaxDynamicSharedMemorySize, 3 * SLOT_BYTES);

  cast_all<<<14336, 256, 0, stream>>>(x, Wq, Wk, Wv, Wo, xb, Wc, Wob);

  // qkv = x @ Wqkv^T   (M=2048, N=3072, K=2048): 8 x 24 = 192 blocks
  gemm8<<<192, 512, 3 * SLOT_BYTES, stream>>>(xb, Wc, qkv, TOK, QKVN, EMB);

  rope_cast<<<14336, 256, 0, stream>>>(qkv, cosT, sinT, Qf, Kf, Vf);

  // causal GQA attention: 4-way kv-split blocks, strip-descending
  attn4<<<64 * 32, 256, 0, stream>>>(Qf, Kf, Vf, ctxb);

  // out = ctx @ Wo^T   (M=N=K=2048): 8 x 16 = 128 blocks
  gemm8<<<128, 512, 3 * SLOT_BYTES, stream>>>(ctxb, Wob, out, TOK, EMB, EMB);
}

// Round 7
// 122.831 us; speedup vs baseline: 1.2781x; 1.2781x over previous
//
#include <hip/hip_runtime.h>
#include <hip/hip_bf16.h>
#include <stdint.h>

#define EMB   2048
#define TOK   2048
#define NH    32
#define NKV   8
#define HD    64
#define QKVN  3072   // 2048 q + 512 k + 512 v

typedef __attribute__((ext_vector_type(8))) short bf16x8;   // 8 bf16 = 4 VGPRs
typedef __attribute__((ext_vector_type(4))) float f32x4;
typedef __attribute__((ext_vector_type(16))) float f32x16;
typedef __attribute__((ext_vector_type(4))) unsigned int u32x4;

__device__ __forceinline__ void gld16(const void* g, void* l) {
  auto gp = reinterpret_cast<const int __attribute__((address_space(1)))*>(
      reinterpret_cast<uintptr_t>(g));
  auto lp = reinterpret_cast<int __attribute__((address_space(3)))*>(
      reinterpret_cast<uintptr_t>(l));
  __builtin_amdgcn_global_load_lds(gp, lp, 16, 0, 0);
}

__device__ __forceinline__ unsigned int cvtpk_bf16(float lo, float hi) {
  unsigned int r;
  asm("v_cvt_pk_bf16_f32 %0, %1, %2" : "=v"(r) : "v"(lo), "v"(hi));
  return r;
}
__device__ __forceinline__ void pl32swap(unsigned int &a, unsigned int &b) {
  asm volatile("v_permlane32_swap_b32 %0, %1" : "+v"(a), "+v"(b));
}
__device__ __forceinline__ float fexp2(float x) {  // v_exp_f32 IS 2^x
  float r;
  asm("v_exp_f32 %0, %1" : "=v"(r) : "v"(x));
  return r;
}

// ---------------------------------------------------------------- cast fp32->bf16
__global__ void cast_all(const float* __restrict__ x,  const float* __restrict__ wq,
                         const float* __restrict__ wk, const float* __restrict__ wv,
                         const float* __restrict__ wo,
                         __hip_bfloat16* __restrict__ xb,
                         __hip_bfloat16* __restrict__ wc,
                         __hip_bfloat16* __restrict__ wob) {
  const size_t M4 = (size_t)4 * 1024 * 1024;
  const size_t M1 = (size_t)1024 * 1024;
  size_t i = ((size_t)blockIdx.x * 256 + threadIdx.x) * 4;
  const float* src;
  __hip_bfloat16* dst;
  if (i < M4)                    { src = x  + i;                 dst = xb  + i; }
  else if (i < 2*M4)             { src = wq + (i - M4);          dst = wc  + (i - M4); }
  else if (i < 2*M4 + M1)        { src = wk + (i - 2*M4);        dst = wc  + M4 + (i - 2*M4); }
  else if (i < 2*M4 + 2*M1)      { src = wv + (i - 2*M4 - M1);   dst = wc  + M4 + M1 + (i - 2*M4 - M1); }
  else                           { src = wo + (i - 2*M4 - 2*M1); dst = wob + (i - 2*M4 - 2*M1); }
  float4 v = *reinterpret_cast<const float4*>(src);
  dst[0] = __float2bfloat16(v.x);
  dst[1] = __float2bfloat16(v.y);
  dst[2] = __float2bfloat16(v.z);
  dst[3] = __float2bfloat16(v.w);
}

// ---------------------------------------------------------------- GEMM  C = A * B^T
// Counted-vmcnt 3-slot schedule (T3+T4), full st-style swizzle (T2): byte col16
// XOR'd with (row&7) — linear gld16 dest + inverse-swz global source + swz ds_read
// (same involution, rule #21). BM=128; BN template (192 -> gemm1 256 blocks,
// 128 -> gemm2 256 blocks; both exactly 1 block/CU). 8 waves (2Mx4N),
// per-wave 64 x BN/4. setprio around MFMA clusters (T5).
template<int BN>
__global__ __launch_bounds__(512) void gemm8(const __hip_bfloat16* __restrict__ A,
                                             const __hip_bfloat16* __restrict__ B,
                                             float* __restrict__ C,
                                             int M, int N, int K) {
  constexpr int A_BYTES = 128 * 128;        // 16 KB (128 rows x 128 B)
  constexpr int B_BYTES = BN * 128;
  constexpr int SLOT    = A_BYTES + B_BYTES;
  constexpr int CA = 2;                     // A staging chunks per wave
  constexpr int CB = BN / 64;               // B staging chunks per wave
  constexpr int NR = BN / 64;               // n-frags per wave
  extern __shared__ char lds[];             // 3 * SLOT

  const int nbc = N / BN;
  const int nwg = gridDim.x;                // 256 (multiple of 8)
  int bid = blockIdx.x;
  bid = (bid & 7) * (nwg >> 3) + (bid >> 3);   // bijective XCD swizzle
  const int br = bid / nbc, bc = bid % nbc;

  const int tid  = threadIdx.x;
  const int w    = tid >> 6;                // wave 0..7
  const int lane = tid & 63;
  const int wr   = w >> 2, wc = w & 3;      // 2 x 4 wave grid
  const int l15  = lane & 15, lg = lane >> 4;
  const int axor = (l15 & 7) << 4;          // read-side byte XOR ((row&7)<<4)

  const __hip_bfloat16* Ag = A + (size_t)br * 128 * K;
  const __hip_bfloat16* Bg = B + (size_t)bc * BN * K;

  // staging: chunk = 8 rows x 128 B; phys slot col16 = lane&7; source col is
  // inverse-swizzled: elem col = ((lane&7) ^ (row&7)) * 8, row&7 = lane>>3.
  const int srow = lane >> 3;
  const int scol = (((lane & 7) ^ srow) << 3);

  auto stageA = [&](char* slot, int kt) {
#pragma unroll
    for (int i = 0; i < CA; ++i) {
      const int c = w * CA + i;
      gld16(Ag + (size_t)(c * 8 + srow) * K + kt + scol, slot + c * 1024);
    }
  };
  auto stageB = [&](char* slot, int kt) {
#pragma unroll
    for (int i = 0; i < CB; ++i) {
      const int c = w * CB + i;
      gld16(Bg + (size_t)(c * 8 + srow) * K + kt + scol, slot + A_BYTES + c * 1024);
    }
  };
  auto ldA = [&](const char* sa, int m, int kk) {
    return *reinterpret_cast<const bf16x8*>(
        sa + (wr * 64 + m * 16 + l15) * 128 + ((kk * 64 + lg * 16) ^ axor));
  };
  auto ldB = [&](const char* sa, int n, int kk) {
    return *reinterpret_cast<const bf16x8*>(
        sa + A_BYTES + (wc * (BN / 4) + n * 16 + l15) * 128 + ((kk * 64 + lg * 16) ^ axor));
  };

  f32x4 acc[4][NR];
#pragma unroll
  for (int m = 0; m < 4; ++m)
#pragma unroll
    for (int n = 0; n < NR; ++n) acc[m][n] = (f32x4){0.f, 0.f, 0.f, 0.f};

  const int nt = K >> 6;                    // 32 K-tiles

  // ---- prologue: stage tiles 0,1 into slots 0,1; drain tile 0
  stageA(lds, 0);         stageB(lds, 0);
  stageA(lds + SLOT, 64); stageB(lds + SLOT, 64);
  if constexpr (CA + CB == 4) asm volatile("s_waitcnt vmcnt(4)" ::: "memory");
  else                        asm volatile("s_waitcnt vmcnt(5)" ::: "memory");
  __builtin_amdgcn_s_barrier();

  int slc = 0, sls = 2;
  for (int t = 0; t < nt; ++t) {
    const char* sa = lds + slc * SLOT;
    char* stg = lds + sls * SLOT;
    const bool do_stage = (t + 2) < nt;
    const int kt2 = (t + 2) << 6;

    bf16x8 afr[2][2], bfr[NR][2];
    // ===== phase 1: ds-read A m0-1 + all B; stage A(t+2)
#pragma unroll
    for (int m = 0; m < 2; ++m)
#pragma unroll
      for (int kk = 0; kk < 2; ++kk) afr[m][kk] = ldA(sa, m, kk);
#pragma unroll
    for (int n = 0; n < NR; ++n)
#pragma unroll
      for (int kk = 0; kk < 2; ++kk) bfr[n][kk] = ldB(sa, n, kk);
    if (do_stage) stageA(stg, kt2);
    __builtin_amdgcn_s_barrier();
    asm volatile("s_waitcnt lgkmcnt(0)" ::: "memory");
    __builtin_amdgcn_sched_barrier(0);
    __builtin_amdgcn_s_setprio(1);
#pragma unroll
    for (int m = 0; m < 2; ++m)
#pragma unroll
      for (int n = 0; n < NR; ++n)
#pragma unroll
        for (int kk = 0; kk < 2; ++kk)
          acc[m][n] = __builtin_amdgcn_mfma_f32_16x16x32_bf16(afr[m][kk], bfr[n][kk],
                                                              acc[m][n], 0, 0, 0);
    __builtin_amdgcn_s_setprio(0);
    __builtin_amdgcn_s_barrier();

    // ===== phase 2: ds-read A m2-3 (B reused); stage B(t+2)
#pragma unroll
    for (int m = 0; m < 2; ++m)
#pragma unroll
      for (int kk = 0; kk < 2; ++kk) afr[m][kk] = ldA(sa, 2 + m, kk);
    if (do_stage) stageB(stg, kt2);
    __builtin_amdgcn_s_barrier();
    asm volatile("s_waitcnt lgkmcnt(0)" ::: "memory");
    __builtin_amdgcn_sched_barrier(0);
    __builtin_amdgcn_s_setprio(1);
#pragma unroll
    for (int m = 0; m < 2; ++m)
#pragma unroll
      for (int n = 0; n < NR; ++n)
#pragma unroll
        for (int kk = 0; kk < 2; ++kk)
          acc[2 + m][n] = __builtin_amdgcn_mfma_f32_16x16x32_bf16(afr[m][kk], bfr[n][kk],
                                                                  acc[2 + m][n], 0, 0, 0);
    __builtin_amdgcn_s_setprio(0);
    if (t < nt - 2) {
      if constexpr (CA + CB == 4) asm volatile("s_waitcnt vmcnt(4)" ::: "memory");
      else                        asm volatile("s_waitcnt vmcnt(5)" ::: "memory");
    } else {
      asm volatile("s_waitcnt vmcnt(0)" ::: "memory");
    }
    __builtin_amdgcn_s_barrier();

    slc = (slc == 2) ? 0 : slc + 1;
    sls = (sls == 2) ? 0 : sls + 1;
  }

  // ---- epilogue: C-write (row = lg*4 + reg, col = l15)
  const int row0 = br * 128 + wr * 64;
  const int col0 = bc * BN + wc * (BN / 4);
#pragma unroll
  for (int m = 0; m < 4; ++m)
#pragma unroll
    for (int n = 0; n < NR; ++n)
#pragma unroll
      for (int r = 0; r < 4; ++r)
        C[(size_t)(row0 + m * 16 + lg * 4 + r) * N + col0 + n * 16 + l15] = acc[m][n][r];
}

// ---------------------------------------------------------------- RoPE + cast to tiled fragment layouts
#define QSCALE 0.1803368801111243f   // 0.125 * log2(e)

__device__ __forceinline__ size_t kq_idx(int tile_row, int t, int d) {
  return ((size_t)tile_row) * 2048 +
         ((((d >> 4) * 64) + (((d >> 3) & 1) * 32) + (t & 31)) << 3) + (d & 7);
}

__global__ void rope_cast(const float* __restrict__ qkv,
                          const float* __restrict__ cosT, const float* __restrict__ sinT,
                          __hip_bfloat16* __restrict__ Qf,
                          __hip_bfloat16* __restrict__ Kf,
                          __hip_bfloat16* __restrict__ Vf) {
  const int QP = TOK * NH * (HD / 2);   // 2,097,152
  const int KP = TOK * NKV * (HD / 2);  //   524,288
  int idx = blockIdx.x * 256 + threadIdx.x;
  if (idx < QP) {
    int d = idx & 31, h = (idx >> 5) & 31, t = idx >> 10;
    const float* row = qkv + (size_t)t * QKVN + h * 64;
    float x1 = row[d], x2 = row[d + 32];
    float o1 = (x1 * cosT[t * 64 + d]      - x2 * sinT[t * 64 + d])      * QSCALE;
    float o2 = (x2 * cosT[t * 64 + d + 32] + x1 * sinT[t * 64 + d + 32]) * QSCALE;
    const int tile_row = h * 64 + (t >> 5);
    Qf[kq_idx(tile_row, t, d)]      = __float2bfloat16(o1);
    Qf[kq_idx(tile_row, t, d + 32)] = __float2bfloat16(o2);
  } else if (idx < QP + KP) {
    int j = idx - QP;
    int d = j & 31, hk = (j >> 5) & 7, t = j >> 8;
    const float* row = qkv + (size_t)t * QKVN + 2048 + hk * 64;
    float x1 = row[d], x2 = row[d + 32];
    float o1 = x1 * cosT[t * 64 + d]      - x2 * sinT[t * 64 + d];
    float o2 = x2 * cosT[t * 64 + d + 32] + x1 * sinT[t * 64 + d + 32];
    const int tile_row = hk * 64 + (t >> 5);
    Kf[kq_idx(tile_row, t, d)]      = __float2bfloat16(o1);
    Kf[kq_idx(tile_row, t, d + 32)] = __float2bfloat16(o2);
  } else {
    int vj = idx - QP - KP;               // d fastest -> coalesced qkv reads
    int d = vj & 63, t = (vj >> 6) & (TOK - 1), hk = vj >> 17;
    float v = qkv[(size_t)t * QKVN + 2560 + hk * 64 + d];
    const size_t tb = ((size_t)hk * 64 + (t >> 5)) * 2048;
    const int c = (((t >> 4) & 1) * 128) + ((d >> 5) * 64) + (((t >> 3) & 1) * 32) + (d & 31);
    Vf[tb + (c << 3) + (t & 7)] = __float2bfloat16(v);
  }
}

// ---------------------------------------------------------------- causal GQA flash attention
// 2-wave blocks (kv-split x2), bf16-packed LDS partials, swapped QK^T + O^T,
// register dbuf prefetch, exp2 softmax, defer-max, TC-layout coalesced loads,
// setprio around MFMA clusters.
struct KVb { bf16x8 k0, k1, k2, k3, v00, v01, v10, v11; };

__device__ __forceinline__ void load_kv(KVb& b, const __hip_bfloat16* Kt,
                                        const __hip_bfloat16* Vt, int tile,
                                        int lane) {
  const __hip_bfloat16* Kp = Kt + (size_t)tile * 2048 + lane * 8;
  b.k0 = *reinterpret_cast<const bf16x8*>(Kp);
  b.k1 = *reinterpret_cast<const bf16x8*>(Kp + 512);
  b.k2 = *reinterpret_cast<const bf16x8*>(Kp + 1024);
  b.k3 = *reinterpret_cast<const bf16x8*>(Kp + 1536);
  const __hip_bfloat16* Vp = Vt + (size_t)tile * 2048 + lane * 8;
  b.v00 = *reinterpret_cast<const bf16x8*>(Vp);
  b.v10 = *reinterpret_cast<const bf16x8*>(Vp + 512);
  b.v01 = *reinterpret_cast<const bf16x8*>(Vp + 1024);
  b.v11 = *reinterpret_cast<const bf16x8*>(Vp + 1536);
}

__device__ __forceinline__ void compute_tile(const KVb& b, bool diag,
                                             const bf16x8 (&qf)[4],
                                             int l31, int hi,
                                             float& m, float& l,
                                             f32x16& oa0, f32x16& oa1) {
  f32x16 st;
#pragma unroll
  for (int r = 0; r < 16; ++r) st[r] = 0.f;
  __builtin_amdgcn_s_setprio(1);
  st = __builtin_amdgcn_mfma_f32_32x32x16_bf16(b.k0, qf[0], st, 0, 0, 0);
  st = __builtin_amdgcn_mfma_f32_32x32x16_bf16(b.k1, qf[1], st, 0, 0, 0);
  st = __builtin_amdgcn_mfma_f32_32x32x16_bf16(b.k2, qf[2], st, 0, 0, 0);
  st = __builtin_amdgcn_mfma_f32_32x32x16_bf16(b.k3, qf[3], st, 0, 0, 0);
  __builtin_amdgcn_s_setprio(0);

  float s[16];
#pragma unroll
  for (int r = 0; r < 16; ++r) s[r] = st[r];
  if (diag) {
#pragma unroll
    for (int r = 0; r < 16; ++r) {
      const int crow = (r & 3) + 8 * (r >> 2) + 4 * hi;
      s[r] = (crow <= l31) ? s[r] : -1e30f;
    }
  }
  float t0 = fmaxf(fmaxf(s[0], s[1]),   fmaxf(s[2], s[3]));
  float t1 = fmaxf(fmaxf(s[4], s[5]),   fmaxf(s[6], s[7]));
  float t2 = fmaxf(fmaxf(s[8], s[9]),   fmaxf(s[10], s[11]));
  float t3 = fmaxf(fmaxf(s[12], s[13]), fmaxf(s[14], s[15]));
  float rmax = fmaxf(fmaxf(t0, t1), fmaxf(t2, t3));
  rmax = fmaxf(rmax, __shfl_xor(rmax, 32));

  const int allskip = __all(rmax <= m + 8.0f);
  const float mnew = allskip ? m : fmaxf(m, rmax);
  float p[16];
#pragma unroll
  for (int r = 0; r < 16; ++r) p[r] = fexp2(s[r] - mnew);
  float u0 = (p[0] + p[1]) + (p[2] + p[3]);
  float u1 = (p[4] + p[5]) + (p[6] + p[7]);
  float u2 = (p[8] + p[9]) + (p[10] + p[11]);
  float u3 = (p[12] + p[13]) + (p[14] + p[15]);
  float rsum = (u0 + u1) + (u2 + u3);
  rsum += __shfl_xor(rsum, 32);
  if (!allskip) {
    const float resc = fexp2(m - mnew);
    l *= resc;
    m = mnew;
#pragma unroll
    for (int r = 0; r < 16; ++r) { oa0[r] *= resc; oa1[r] *= resc; }
  }
  l += rsum;

  unsigned int wpk[8];
#pragma unroll
  for (int j = 0; j < 8; ++j) wpk[j] = cvtpk_bf16(p[2 * j], p[2 * j + 1]);

  __builtin_amdgcn_s_setprio(1);
  {
    unsigned int a0 = wpk[0], b0 = wpk[2];  pl32swap(a0, b0);
    unsigned int a1 = wpk[1], b1 = wpk[3];  pl32swap(a1, b1);
    u32x4 pw; pw[0] = a0; pw[1] = a1; pw[2] = b0; pw[3] = b1;
    bf16x8 pf = *reinterpret_cast<bf16x8*>(&pw);
    oa0 = __builtin_amdgcn_mfma_f32_32x32x16_bf16(b.v00, pf, oa0, 0, 0, 0);
    oa1 = __builtin_amdgcn_mfma_f32_32x32x16_bf16(b.v10, pf, oa1, 0, 0, 0);
  }
  {
    unsigned int a0 = wpk[4], b0 = wpk[6];  pl32swap(a0, b0);
    unsigned int a1 = wpk[5], b1 = wpk[7];  pl32swap(a1, b1);
    u32x4 pw; pw[0] = a0; pw[1] = a1; pw[2] = b0; pw[3] = b1;
    bf16x8 pf = *reinterpret_cast<bf16x8*>(&pw);
    oa0 = __builtin_amdgcn_mfma_f32_32x32x16_bf16(b.v01, pf, oa0, 0, 0, 0);
    oa1 = __builtin_amdgcn_mfma_f32_32x32x16_bf16(b.v11, pf, oa1, 0, 0, 0);
  }
  __builtin_amdgcn_s_setprio(0);
}

// grid = 64 strips (desc) * 32 heads; block = 128 (2 waves = 2 kv-splits)
__global__ __launch_bounds__(128) void attn5(const __hip_bfloat16* __restrict__ Qf,
                                             const __hip_bfloat16* __restrict__ Kf,
                                             const __hip_bfloat16* __restrict__ Vf,
                                             __hip_bfloat16* __restrict__ ctx) {
  const int h     = blockIdx.x & 31;
  const int strip = 63 - (blockIdx.x >> 5);
  const int hk    = h >> 2;
  const int tid   = threadIdx.x;
  const int w     = tid >> 6;                  // kv-split 0..1
  const int lane  = tid & 63;
  const int l31   = lane & 31, hi = lane >> 5;
  const int q0    = strip * 32;
  const int nt    = strip + 1;

  __shared__ unsigned int part_u[2][32][33];   // packed bf16 (lo=d, hi=d+32)
  __shared__ float mlb[2][2][32];

  const __hip_bfloat16* Kt = Kf + (size_t)hk * 64 * 2048;
  const __hip_bfloat16* Vt = Vf + (size_t)hk * 64 * 2048;

  const __hip_bfloat16* Qp = Qf + ((size_t)h * 64 + strip) * 2048 + lane * 8;
  bf16x8 qf[4];
#pragma unroll
  for (int ks = 0; ks < 4; ++ks)
    qf[ks] = *reinterpret_cast<const bf16x8*>(Qp + ks * 512);

  f32x16 oa0, oa1;
#pragma unroll
  for (int r = 0; r < 16; ++r) { oa0[r] = 0.f; oa1[r] = 0.f; }
  float m = -1e30f, l = 0.f;

  if (w < nt) {                                // wave-uniform
    KVb A, B;
    load_kv(A, Kt, Vt, w, lane);
    int t = w;
    for (;;) {
      int nx = t + 2;
      if (nx < nt) load_kv(B, Kt, Vt, nx, lane);
      compute_tile(A, t == nt - 1, qf, l31, hi, m, l, oa0, oa1);
      t = nx;
      if (t >= nt) break;
      nx = t + 2;
      if (nx < nt) load_kv(A, Kt, Vt, nx, lane);
      compute_tile(B, t == nt - 1, qf, l31, hi, m, l, oa0, oa1);
      t = nx;
      if (t >= nt) break;
    }
  }

  // ---- partials to LDS (bf16-packed)
#pragma unroll
  for (int r = 0; r < 16; ++r) {
    const int d0 = (r & 3) + 8 * (r >> 2) + 4 * hi;   // 0..31
    part_u[w][d0][l31] = cvtpk_bf16(oa0[r], oa1[r]);
  }
  if (hi == 0) { mlb[w][0][l31] = m; mlb[w][1][l31] = l; }
  __syncthreads();

  // ---- merge 2 partials + write ctx (coalesced: lanes span d)
  const int d  = tid & 63;
  const int qg = tid >> 6;
#pragma unroll
  for (int qq = 0; qq < 16; ++qq) {
    const int q = qg * 16 + qq;
    const float m0 = mlb[0][0][q], m1 = mlb[1][0][q];
    const float M = fmaxf(m0, m1);
    const float s0 = fexp2(m0 - M), s1 = fexp2(m1 - M);
    const float L = mlb[0][1][q] * s0 + mlb[1][1][q] * s1;
    const unsigned int u0 = part_u[0][d & 31][q];
    const unsigned int u1 = part_u[1][d & 31][q];
    const unsigned int w0 = (d < 32) ? (u0 << 16) : (u0 & 0xffff0000u);
    const unsigned int w1 = (d < 32) ? (u1 << 16) : (u1 & 0xffff0000u);
    const float p0 = __uint_as_float(w0), p1 = __uint_as_float(w1);
    ctx[(size_t)(q0 + q) * EMB + h * HD + d] = __float2bfloat16((p0 * s0 + p1 * s1) / L);
  }
}

// ---------------------------------------------------------------- launch
extern "C" void kernel_launch(void* const* d_in, const int* in_sizes, int n_in,
                              void* d_out, int out_size, void* d_ws, size_t ws_size,
                              hipStream_t stream) {
  const float* x    = (const float*)d_in[0];
  const float* cosT = (const float*)d_in[1];
  const float* sinT = (const float*)d_in[2];
  const float* Wq   = (const float*)d_in[3];
  const float* Wk   = (const float*)d_in[4];
  const float* Wv   = (const float*)d_in[5];
  const float* Wo   = (const float*)d_in[6];
  float* out = (float*)d_out;

  const size_t M4 = (size_t)4 * 1024 * 1024;
  const size_t M1 = (size_t)1024 * 1024;

  char* ws = (char*)d_ws;
  __hip_bfloat16* xb   = (__hip_bfloat16*)ws;
  __hip_bfloat16* Wc   = xb + M4;
  __hip_bfloat16* Wob  = Wc + (size_t)6 * M1;
  float*          qkv  = (float*)(Wob + M4);
  __hip_bfloat16* Qf   = (__hip_bfloat16*)(qkv + (size_t)TOK * QKVN);
  __hip_bfloat16* Kf   = Qf + (size_t)NH * TOK * HD;
  __hip_bfloat16* Vf   = Kf + (size_t)NKV * TOK * HD;
  __hip_bfloat16* ctxb = Vf + (size_t)NKV * HD * TOK;

  constexpr int SLOT192 = 128 * 128 + 192 * 128;   // 40960
  constexpr int SLOT128 = 128 * 128 + 128 * 128;   // 32768
  hipFuncSetAttribute(reinterpret_cast<const void*>(&gemm8<192>),
                      hipFuncAttributeMaxDynamicSharedMemorySize, 3 * SLOT192);
  hipFuncSetAttribute(reinterpret_cast<const void*>(&gemm8<128>),
                      hipFuncAttributeMaxDynamicSharedMemorySize, 3 * SLOT128);

  cast_all<<<14336, 256, 0, stream>>>(x, Wq, Wk, Wv, Wo, xb, Wc, Wob);

  // qkv = x @ Wqkv^T   (M=2048, N=3072, K=2048): 16 x 16 = 256 blocks
  gemm8<192><<<256, 512, 3 * SLOT192, stream>>>(xb, Wc, qkv, TOK, QKVN, EMB);

  rope_cast<<<14336, 256, 0, stream>>>(qkv, cosT, sinT, Qf, Kf, Vf);

  // causal GQA attention: 2-wave kv-split blocks, strip-descending
  attn5<<<64 * 32, 128, 0, stream>>>(Qf, Kf, Vf, ctxb);

  // out = ctx @ Wo^T   (M=N=K=2048): 16 x 16 = 256 blocks
  gemm8<128><<<256, 512, 3 * SLOT128, stream>>>(ctxb, Wob, out, TOK, EMB, EMB);
}